// Round 8
// baseline (53.328 us; speedup 1.0000x reference)
//
#include <hip/hip_runtime.h>
#include <math.h>

// VisionPooler: B=32, SEQ=2520 (84x30 grid), HIDDEN=768, OUT_LEN=280, k=3.
// out = concat( [B,280,768] pooled f32 , [B,280] mask-as-f32 ).
//
// SINGLE fused kernel, one block per (bucket l, batch b), 192 threads.
// Each block redundantly verifies its batch's pos is the regular grid
// (x==s%84, y==s/84): 20KB/batch re-read by 280 blocks -> L2-amplified,
// ~5MB HBM total, hidden under the hs stream. Removes the separate verify
// dispatch + inter-kernel drain.
//   fast (regular): 9 source rows by formula + 9 uniform pad loads.
//   slow (irregular batch): rescan batch pos (L2-hot) for max_x and for the
//     <=CAP patches with seg==l; sort -> deterministic sum order.
// hs loads / out stores non-temporal (zero reuse); pos/padding normal loads.

#define NB    32
#define SEQL  2520
#define HID   768
#define OUTL  280
#define CAP   16
#define GX    84        // grid x extent when regular
#define KP    3         // pool factor
#define MXK   (GX / KP) // 28 buckets per row when regular

typedef float f32x4 __attribute__((ext_vector_type(4)));

__global__ void __launch_bounds__(192)
k_fused(const float* __restrict__ hs, const int* __restrict__ pos,
        const int* __restrict__ padding, float* __restrict__ out,
        float* __restrict__ out_mask, float scale) {
    __shared__ int sok[3];
    __shared__ int smx[3];
    __shared__ int s_cnt;
    __shared__ int s_ent[CAP];

    const int l = blockIdx.x;
    const int b = blockIdx.y;
    const int t = threadIdx.x;
    const int bl = b * OUTL + l;
    const int* p = pos + (size_t)b * SEQL * 2;
    const int4* p4 = (const int4*)p;           // {x0,y0,x1,y1} per 2 patches

    // ---- redundant per-block regularity check of batch b (L2-hot) ----
    int ok = 1;
    for (int i = t; i < SEQL / 2; i += 192) {  // 1260 int4s, <=7 iters
        int4 v = p4[i];
        int s0 = 2 * i, s1 = 2 * i + 1;
        ok &= (v.x == s0 % GX) & (v.y == s0 / GX)
            & (v.z == s1 % GX) & (v.w == s1 / GX);
    }
    ok = __all(ok);
    if ((t & 63) == 0) sok[t >> 6] = ok;
    __syncthreads();
    const int fast = sok[0] & sok[1] & sok[2];

    int e[9];                             // (s<<1)|pad, ascending s
    if (fast) {
        const int s00 = (KP * (l / MXK)) * GX + KP * (l % MXK);
        #pragma unroll
        for (int dy = 0; dy < 3; ++dy)
            #pragma unroll
            for (int dx = 0; dx < 3; ++dx) {
                int s = s00 + dy * GX + dx;
                e[dy * 3 + dx] = (s << 1) | (padding[b * SEQL + s] != 0 ? 1 : 0);
            }
        if (t == 0) out_mask[bl] = 1.0f;  // every bucket gets 9 patches
    } else {
        // ---- generic fallback (batch pos is L2-resident now) ----
        int m = 0;
        for (int i = t; i < SEQL / 2; i += 192) {
            int4 v = p4[i];
            int cx = v.x < 0 ? 0 : v.x; if (cx > m) m = cx;
            cx = v.z < 0 ? 0 : v.z;     if (cx > m) m = cx;
        }
        #pragma unroll
        for (int off = 32; off > 0; off >>= 1) {
            int o = __shfl_down(m, off, 64);
            if (o > m) m = o;
        }
        if ((t & 63) == 0) smx[t >> 6] = m;
        if (t == 0) s_cnt = 0;
        __syncthreads();
        int mx = smx[0]; if (smx[1] > mx) mx = smx[1]; if (smx[2] > mx) mx = smx[2];
        const int mxk = (mx + 1) / KP;
        const int* pd = padding + (size_t)b * SEQL;
        for (int s = t; s < SEQL; s += 192) {
            int x = p[2 * s];     if (x < 0) x = 0;
            int y = p[2 * s + 1]; if (y < 0) y = 0;
            int seg = x / KP + mxk * (y / KP);
            if (seg == l) {                // this block's bucket only
                int sl = atomicAdd(&s_cnt, 1);
                if (sl < CAP) s_ent[sl] = (s << 1) | (pd[s] != 0 ? 1 : 0);
            }
        }
        __syncthreads();
        const int n = s_cnt < CAP ? s_cnt : CAP;
        #pragma unroll
        for (int i = 0; i < 9; ++i) e[i] = (i < n) ? s_ent[i] : 1; // sentinel
        #pragma unroll
        for (int i = 1; i < 9; ++i) {     // sort ascending: deterministic order
            int v = e[i], j = i - 1;
            while (j >= 0 && e[j] > v) { e[j + 1] = e[j]; --j; }
            e[j + 1] = v;
        }
        if (t == 0) out_mask[bl] = (s_cnt > 0) ? 1.0f : 0.0f;
    }

    // ---- bulk gather-accumulate ----
    f32x4 acc = (f32x4)(0.f);
    const f32x4* base = (const f32x4*)(hs + (size_t)b * SEQL * HID);
    #pragma unroll
    for (int i = 0; i < 9; ++i) {
        if (!(e[i] & 1)) {                // block-uniform -> no divergence
            f32x4 v = __builtin_nontemporal_load(
                base + (size_t)(e[i] >> 1) * (HID / 4) + t);
            acc += v;
        }
    }
    acc *= scale;
    __builtin_nontemporal_store(acc, (f32x4*)(out + (size_t)bl * HID) + t);
}

extern "C" void kernel_launch(void* const* d_in, const int* in_sizes, int n_in,
                              void* d_out, int out_size, void* d_ws, size_t ws_size,
                              hipStream_t stream) {
    const float* hs      = (const float*)d_in[0];
    const int*   pos     = (const int*)d_in[1];
    const int*   padding = (const int*)d_in[2]; // jax bool -> 4-byte on device
    // d_in[3] = output_length scalar (unused; shapes fixed: 2520 -> 280, k=3)

    float* out      = (float*)d_out;
    float* out_mask = out + (size_t)NB * OUTL * HID;
    const float scale = sqrtf((float)HID) / 9.0f;   // *sqrt(768) / k^2

    dim3 grid(OUTL, NB);
    k_fused<<<grid, 192, 0, stream>>>(hs, pos, padding, out, out_mask, scale);
}

// Round 9
// 51.408 us; speedup vs baseline: 1.0373x; 1.0373x over previous
//
#include <hip/hip_runtime.h>
#include <math.h>

// VisionPooler: B=32, SEQ=2520 (84x30 grid), HIDDEN=768, OUT_LEN=280, k=3.
// out = concat( [B,280,768] pooled f32 , [B,280] mask-as-f32 ).
//
// k_verify (8x32 blocks, pure check): sub-block j of batch b checks patches
//   [j*315,(j+1)*315) for pos==(s%84, s/84); writes flags[b*8+j]. ~1-1.5us.
// k_pool (280x32 blocks, 192 thr, no LDS in fast path): ANDs 8 sub-flags.
//   fast: 9 source rows by formula + 9 uniform pad loads, mask=1.
//   slow (irregular batch, never on bench data): in-block L2-hot rescan of
//   batch pos for max_x and the <=CAP patches with seg==l; sorted sum.
// hs loads / out stores non-temporal (zero reuse); pos/padding normal loads.
// ws: int flags[256] @0.

#define NB    32
#define SEQL  2520
#define HID   768
#define OUTL  280
#define CAP   16
#define GX    84        // grid x extent when regular
#define KP    3         // pool factor
#define MXK   (GX / KP) // 28 buckets per row when regular
#define VSPL  8         // verify sub-blocks per batch
#define VCHK  (SEQL / VSPL) // 315 patches per sub-block

typedef float f32x4 __attribute__((ext_vector_type(4)));

__global__ void __launch_bounds__(256)
k_verify(const int* __restrict__ pos, int* __restrict__ flags) {
    __shared__ int sok[4];
    const int j = blockIdx.x;            // 0..7
    const int b = blockIdx.y;
    const int t = threadIdx.x;
    const int2* p2 = (const int2*)(pos + (size_t)b * SEQL * 2); // {x,y}/patch

    int ok = 1;
    for (int s = j * VCHK + t; s < (j + 1) * VCHK; s += 256) {  // <=2 iters
        int2 v = p2[s];
        ok &= (v.x == s % GX) & (v.y == s / GX);
    }
    ok = __all(ok);
    if ((t & 63) == 0) sok[t >> 6] = ok;
    __syncthreads();
    if (t == 0) flags[b * VSPL + j] = sok[0] & sok[1] & sok[2] & sok[3];
}

// One block per (bucket l, batch b). 192 threads, one float4 of HID each.
__global__ void __launch_bounds__(192)
k_pool(const float* __restrict__ hs, const int* __restrict__ pos,
       const int* __restrict__ padding, const int* __restrict__ flags,
       float* __restrict__ out, float* __restrict__ out_mask, float scale) {
    __shared__ int smx[3];
    __shared__ int s_cnt;
    __shared__ int s_ent[CAP];
    const int l = blockIdx.x;
    const int b = blockIdx.y;
    const int t = threadIdx.x;
    const int bl = b * OUTL + l;

    const int* fb = flags + b * VSPL;    // uniform scalar loads
    const int fast = fb[0] & fb[1] & fb[2] & fb[3] & fb[4] & fb[5] & fb[6] & fb[7];

    int e[9];                            // (s<<1)|pad, ascending s
    if (fast) {
        const int s00 = (KP * (l / MXK)) * GX + KP * (l % MXK);
        #pragma unroll
        for (int dy = 0; dy < 3; ++dy)
            #pragma unroll
            for (int dx = 0; dx < 3; ++dx) {
                int s = s00 + dy * GX + dx;
                e[dy * 3 + dx] = (s << 1) | (padding[b * SEQL + s] != 0 ? 1 : 0);
            }
        if (t == 0) out_mask[bl] = 1.0f; // every bucket gets 9 patches
    } else {
        // ---- generic fallback: in-block rescan (batch pos is L2-hot) ----
        const int* p = pos + (size_t)b * SEQL * 2;
        const int4* p4 = (const int4*)p;
        int m = 0;
        for (int i = t; i < SEQL / 2; i += 192) {
            int4 v = p4[i];
            int cx = v.x < 0 ? 0 : v.x; if (cx > m) m = cx;
            cx = v.z < 0 ? 0 : v.z;     if (cx > m) m = cx;
        }
        #pragma unroll
        for (int off = 32; off > 0; off >>= 1) {
            int o = __shfl_down(m, off, 64);
            if (o > m) m = o;
        }
        if ((t & 63) == 0) smx[t >> 6] = m;
        if (t == 0) s_cnt = 0;
        __syncthreads();
        int mx = smx[0]; if (smx[1] > mx) mx = smx[1]; if (smx[2] > mx) mx = smx[2];
        const int mxk = (mx + 1) / KP;
        const int* pd = padding + (size_t)b * SEQL;
        for (int s = t; s < SEQL; s += 192) {
            int x = p[2 * s];     if (x < 0) x = 0;
            int y = p[2 * s + 1]; if (y < 0) y = 0;
            int seg = x / KP + mxk * (y / KP);
            if (seg == l) {               // this block's bucket only
                int sl = atomicAdd(&s_cnt, 1);
                if (sl < CAP) s_ent[sl] = (s << 1) | (pd[s] != 0 ? 1 : 0);
            }
        }
        __syncthreads();
        const int n = s_cnt < CAP ? s_cnt : CAP;
        #pragma unroll
        for (int i = 0; i < 9; ++i) e[i] = (i < n) ? s_ent[i] : 1; // sentinel
        #pragma unroll
        for (int i = 1; i < 9; ++i) {    // sort ascending: deterministic order
            int v = e[i], j = i - 1;
            while (j >= 0 && e[j] > v) { e[j + 1] = e[j]; --j; }
            e[j + 1] = v;
        }
        if (t == 0) out_mask[bl] = (s_cnt > 0) ? 1.0f : 0.0f;
    }

    // ---- bulk gather-accumulate ----
    f32x4 acc = (f32x4)(0.f);
    const f32x4* base = (const f32x4*)(hs + (size_t)b * SEQL * HID);
    #pragma unroll
    for (int i = 0; i < 9; ++i) {
        if (!(e[i] & 1)) {               // block-uniform -> no divergence
            f32x4 v = __builtin_nontemporal_load(
                base + (size_t)(e[i] >> 1) * (HID / 4) + t);
            acc += v;
        }
    }
    acc *= scale;
    __builtin_nontemporal_store(acc, (f32x4*)(out + (size_t)bl * HID) + t);
}

extern "C" void kernel_launch(void* const* d_in, const int* in_sizes, int n_in,
                              void* d_out, int out_size, void* d_ws, size_t ws_size,
                              hipStream_t stream) {
    const float* hs      = (const float*)d_in[0];
    const int*   pos     = (const int*)d_in[1];
    const int*   padding = (const int*)d_in[2]; // jax bool -> 4-byte on device
    // d_in[3] = output_length scalar (unused; shapes fixed: 2520 -> 280, k=3)

    int* flags = (int*)d_ws;                    // [32*8]

    float* out      = (float*)d_out;
    float* out_mask = out + (size_t)NB * OUTL * HID;
    const float scale = sqrtf((float)HID) / 9.0f;   // *sqrt(768) / k^2

    dim3 vgrid(VSPL, NB);
    k_verify<<<vgrid, 256, 0, stream>>>(pos, flags);
    dim3 grid(OUTL, NB);
    k_pool<<<grid, 192, 0, stream>>>(hs, pos, padding, flags, out, out_mask, scale);
}

// Round 10
// 46.869 us; speedup vs baseline: 1.1378x; 1.0968x over previous
//
#include <hip/hip_runtime.h>
#include <math.h>

// VisionPooler: B=32, SEQ=2520 (84x30 grid), HIDDEN=768, OUT_LEN=280, k=3.
// out = concat( [B,280,768] pooled f32 , [B,280] mask-as-f32 ).
//
// R9 structure; single change: hs loads are NORMAL (L2-allocating) instead of
// non-temporal -- A/B to test whether nt reads are demoted by TCC. Stores
// remain non-temporal.
//
// k_verify (8x32 blocks, pure check): sub-block j of batch b checks patches
//   [j*315,(j+1)*315) for pos==(s%84, s/84); writes flags[b*8+j].
// k_pool (280x32 blocks, 192 thr): ANDs 8 sub-flags.
//   fast: 9 source rows by formula + 9 uniform pad loads, mask=1.
//   slow (irregular batch, never on bench data): in-block L2-hot rescan.
// ws: int flags[256] @0.

#define NB    32
#define SEQL  2520
#define HID   768
#define OUTL  280
#define CAP   16
#define GX    84        // grid x extent when regular
#define KP    3         // pool factor
#define MXK   (GX / KP) // 28 buckets per row when regular
#define VSPL  8         // verify sub-blocks per batch
#define VCHK  (SEQL / VSPL) // 315 patches per sub-block

typedef float f32x4 __attribute__((ext_vector_type(4)));

__global__ void __launch_bounds__(256)
k_verify(const int* __restrict__ pos, int* __restrict__ flags) {
    __shared__ int sok[4];
    const int j = blockIdx.x;            // 0..7
    const int b = blockIdx.y;
    const int t = threadIdx.x;
    const int2* p2 = (const int2*)(pos + (size_t)b * SEQL * 2); // {x,y}/patch

    int ok = 1;
    for (int s = j * VCHK + t; s < (j + 1) * VCHK; s += 256) {  // <=2 iters
        int2 v = p2[s];
        ok &= (v.x == s % GX) & (v.y == s / GX);
    }
    ok = __all(ok);
    if ((t & 63) == 0) sok[t >> 6] = ok;
    __syncthreads();
    if (t == 0) flags[b * VSPL + j] = sok[0] & sok[1] & sok[2] & sok[3];
}

// One block per (bucket l, batch b). 192 threads, one float4 of HID each.
__global__ void __launch_bounds__(192)
k_pool(const float* __restrict__ hs, const int* __restrict__ pos,
       const int* __restrict__ padding, const int* __restrict__ flags,
       float* __restrict__ out, float* __restrict__ out_mask, float scale) {
    __shared__ int smx[3];
    __shared__ int s_cnt;
    __shared__ int s_ent[CAP];
    const int l = blockIdx.x;
    const int b = blockIdx.y;
    const int t = threadIdx.x;
    const int bl = b * OUTL + l;

    const int* fb = flags + b * VSPL;    // uniform scalar loads
    const int fast = fb[0] & fb[1] & fb[2] & fb[3] & fb[4] & fb[5] & fb[6] & fb[7];

    int e[9];                            // (s<<1)|pad, ascending s
    if (fast) {
        const int s00 = (KP * (l / MXK)) * GX + KP * (l % MXK);
        #pragma unroll
        for (int dy = 0; dy < 3; ++dy)
            #pragma unroll
            for (int dx = 0; dx < 3; ++dx) {
                int s = s00 + dy * GX + dx;
                e[dy * 3 + dx] = (s << 1) | (padding[b * SEQL + s] != 0 ? 1 : 0);
            }
        if (t == 0) out_mask[bl] = 1.0f; // every bucket gets 9 patches
    } else {
        // ---- generic fallback: in-block rescan (batch pos is L2-hot) ----
        const int* p = pos + (size_t)b * SEQL * 2;
        const int4* p4 = (const int4*)p;
        int m = 0;
        for (int i = t; i < SEQL / 2; i += 192) {
            int4 v = p4[i];
            int cx = v.x < 0 ? 0 : v.x; if (cx > m) m = cx;
            cx = v.z < 0 ? 0 : v.z;     if (cx > m) m = cx;
        }
        #pragma unroll
        for (int off = 32; off > 0; off >>= 1) {
            int o = __shfl_down(m, off, 64);
            if (o > m) m = o;
        }
        if ((t & 63) == 0) smx[t >> 6] = m;
        if (t == 0) s_cnt = 0;
        __syncthreads();
        int mx = smx[0]; if (smx[1] > mx) mx = smx[1]; if (smx[2] > mx) mx = smx[2];
        const int mxk = (mx + 1) / KP;
        const int* pd = padding + (size_t)b * SEQL;
        for (int s = t; s < SEQL; s += 192) {
            int x = p[2 * s];     if (x < 0) x = 0;
            int y = p[2 * s + 1]; if (y < 0) y = 0;
            int seg = x / KP + mxk * (y / KP);
            if (seg == l) {               // this block's bucket only
                int sl = atomicAdd(&s_cnt, 1);
                if (sl < CAP) s_ent[sl] = (s << 1) | (pd[s] != 0 ? 1 : 0);
            }
        }
        __syncthreads();
        const int n = s_cnt < CAP ? s_cnt : CAP;
        #pragma unroll
        for (int i = 0; i < 9; ++i) e[i] = (i < n) ? s_ent[i] : 1; // sentinel
        #pragma unroll
        for (int i = 1; i < 9; ++i) {    // sort ascending: deterministic order
            int v = e[i], j = i - 1;
            while (j >= 0 && e[j] > v) { e[j + 1] = e[j]; --j; }
            e[j + 1] = v;
        }
        if (t == 0) out_mask[bl] = (s_cnt > 0) ? 1.0f : 0.0f;
    }

    // ---- bulk gather-accumulate (normal loads: A/B vs nt) ----
    f32x4 acc = (f32x4)(0.f);
    const f32x4* base = (const f32x4*)(hs + (size_t)b * SEQL * HID);
    #pragma unroll
    for (int i = 0; i < 9; ++i) {
        if (!(e[i] & 1)) {               // block-uniform -> no divergence
            f32x4 v = base[(size_t)(e[i] >> 1) * (HID / 4) + t];
            acc += v;
        }
    }
    acc *= scale;
    __builtin_nontemporal_store(acc, (f32x4*)(out + (size_t)bl * HID) + t);
}

extern "C" void kernel_launch(void* const* d_in, const int* in_sizes, int n_in,
                              void* d_out, int out_size, void* d_ws, size_t ws_size,
                              hipStream_t stream) {
    const float* hs      = (const float*)d_in[0];
    const int*   pos     = (const int*)d_in[1];
    const int*   padding = (const int*)d_in[2]; // jax bool -> 4-byte on device
    // d_in[3] = output_length scalar (unused; shapes fixed: 2520 -> 280, k=3)

    int* flags = (int*)d_ws;                    // [32*8]

    float* out      = (float*)d_out;
    float* out_mask = out + (size_t)NB * OUTL * HID;
    const float scale = sqrtf((float)HID) / 9.0f;   // *sqrt(768) / k^2

    dim3 vgrid(VSPL, NB);
    k_verify<<<vgrid, 256, 0, stream>>>(pos, flags);
    dim3 grid(OUTL, NB);
    k_pool<<<grid, 192, 0, stream>>>(hs, pos, padding, flags, out, out_mask, scale);
}